// Round 17
// baseline (589.584 us; speedup 1.0000x reference)
//
#include <hip/hip_runtime.h>

#define NN 32768
#define NE 1048576
#define BCAP 5120  // per-bucket capacity; mean 4096, sigma 64 -> 16 sigma headroom

typedef __bf16 bf16_t;
typedef __bf16 bf16x8 __attribute__((ext_vector_type(8)));
typedef __bf16 bf16x4 __attribute__((ext_vector_type(4)));
typedef float f32x4 __attribute__((ext_vector_type(4)));
typedef unsigned int u32;
typedef unsigned short u16;

// ---------------- prologue: weight-frag prep | node encoder ----------------
// wfr layout (72 frags x 512), all 16x16 frags (lane: dim=nt*16+(l&15), k=kt*32+(l>>4)*8+i):
//   0-23 Weu1 | 24-31 Weu2 | 32-39 Wee2 | 40-47 Wd1 | 48-63 Wnu1 (K=128) | 64-71 Wnu2
__global__ __launch_bounds__(256) void prep_encode_kernel(
    const float* __restrict__ Weu1, const float* __restrict__ Weu2,
    const float* __restrict__ Wee2, const float* __restrict__ Wd1,
    const float* __restrict__ Wnu1, const float* __restrict__ Wnu2,
    bf16_t* __restrict__ wfr,
    const float* __restrict__ nodes, const float* __restrict__ Wne1,
    const float* __restrict__ bne1, const float* __restrict__ Wne2,
    const float* __restrict__ bne2, bf16_t* __restrict__ n_bf) {
  const int b = blockIdx.x, tid = threadIdx.x;
  if (b < 144) {
    int idx = b * 256 + tid;  // < 36864 = 72 frags
    int i = idx & 7, lane = (idx >> 3) & 63, f = idx >> 9;
    const float* W;
    int fl;
    if (f < 24)      { W = Weu1; fl = f; }
    else if (f < 32) { W = Weu2; fl = f - 24; }
    else if (f < 40) { W = Wee2; fl = f - 32; }
    else if (f < 48) { W = Wd1;  fl = f - 40; }
    else if (f < 64) { W = Wnu1; fl = f - 48; }
    else             { W = Wnu2; fl = f - 64; }
    int kt = fl >> 2, nt = fl & 3;
    int k = kt * 32 + ((lane >> 4) << 3) + i;
    int col = nt * 16 + (lane & 15);
    wfr[idx] = (bf16_t)W[k * 64 + col];
  } else {
    __shared__ float hs[4][64];
    int wid = tid >> 6, k = tid & 63;
    int node = (b - 144) * 4 + wid;
    float x = nodes[node];
    hs[wid][k] = fmaxf(x * Wne1[k] + bne1[k], 0.0f);
    __syncthreads();
    float acc = bne2[k];
#pragma unroll 8
    for (int j = 0; j < 64; ++j) acc = fmaf(hs[wid][j], Wne2[j * 64 + k], acc);
    n_bf[(size_t)node * 64 + k] = (bf16_t)acc;
  }
}

// ---------------- CSR build, level 1: coarse 256-bucket scatter + absmax ----------------
__global__ __launch_bounds__(256) void coarse_kernel(
    const float* __restrict__ edges_init, const int* __restrict__ recv,
    float* __restrict__ norm, u32* __restrict__ ccur,
    u16* __restrict__ bkt_r, u32* __restrict__ bkt_o) {
  __shared__ u32 hist[256];
  __shared__ u32 base[256];
  __shared__ float mred[4];
  const int tid = threadIdx.x, lane = tid & 63, wid = tid >> 6;
  const int idx = blockIdx.x * 256 + tid;
  hist[tid] = 0;
  __syncthreads();
  int4 r = reinterpret_cast<const int4*>(recv)[idx];
  float4 v = reinterpret_cast<const float4*>(edges_init)[idx];
  float m = fmaxf(fmaxf(fabsf(v.x), fabsf(v.y)), fmaxf(fabsf(v.z), fabsf(v.w)));
#pragma unroll
  for (int off = 32; off > 0; off >>= 1) m = fmaxf(m, __shfl_xor(m, off, 64));
  if (lane == 0) mred[wid] = m;
  atomicAdd(&hist[r.x >> 7], 1u);
  atomicAdd(&hist[r.y >> 7], 1u);
  atomicAdd(&hist[r.z >> 7], 1u);
  atomicAdd(&hist[r.w >> 7], 1u);
  __syncthreads();
  if (tid == 0) {
    float mm = fmaxf(fmaxf(mred[0], mred[1]), fmaxf(mred[2], mred[3]));
    atomicMax(reinterpret_cast<u32*>(norm), __float_as_uint(mm));
  }
  u32 h = hist[tid];
  if (h) base[tid] = atomicAdd(&ccur[tid], h);
  hist[tid] = 0;  // reuse as block-local cursor
  __syncthreads();
  const int e0 = idx * 4;
  int rv4[4] = {r.x, r.y, r.z, r.w};
#pragma unroll
  for (int q = 0; q < 4; ++q) {
    int rv = rv4[q], bk = rv >> 7;
    u32 loc = atomicAdd(&hist[bk], 1u);
    u32 pos = (u32)bk * BCAP + base[bk] + loc;
    bkt_r[pos] = (u16)rv;
    bkt_o[pos] = (u32)(e0 + q);
  }
}

__global__ __launch_bounds__(256) void scan256_kernel(const u32* __restrict__ ccur,
                                                      u32* __restrict__ bbase,
                                                      int* __restrict__ row_ptr) {
  __shared__ u32 s[256];
  const int tid = threadIdx.x;
  s[tid] = ccur[tid];
  __syncthreads();
  if (tid == 0) {
    u32 run = 0;
    for (int j = 0; j < 256; ++j) {
      u32 c = s[j];
      s[j] = run;
      run += c;
    }
    row_ptr[NN] = (int)run;
  }
  __syncthreads();
  bbase[tid] = s[tid];
}

__global__ __launch_bounds__(1024) void bucket_kernel(
    const u32* __restrict__ ccur, const u32* __restrict__ bbase,
    const u16* __restrict__ bkt_r, const u32* __restrict__ bkt_o,
    const int* __restrict__ senders, const float* __restrict__ edges_init,
    int* __restrict__ row_ptr, int* __restrict__ col_idx,
    int* __restrict__ s_perm, int* __restrict__ r_perm, float* __restrict__ x_perm) {
  __shared__ u32 hist[128];
  __shared__ u32 cur[128];
  const int b = blockIdx.x, tid = threadIdx.x;
  const u32 sz = ccur[b], bb = bbase[b];
  if (tid < 128) hist[tid] = 0;
  __syncthreads();
  for (u32 i = tid; i < sz; i += 1024) atomicAdd(&hist[bkt_r[(u32)b * BCAP + i] & 127], 1u);
  __syncthreads();
  if (tid == 0) {
    u32 run = 0;
    for (int j = 0; j < 128; ++j) {
      u32 c = hist[j];
      hist[j] = run;
      cur[j] = run;
      run += c;
    }
  }
  __syncthreads();
  if (tid < 128) row_ptr[b * 128 + tid] = (int)(bb + hist[tid]);
  for (u32 i = tid; i < sz; i += 1024) {
    int rv = (int)bkt_r[(u32)b * BCAP + i];
    int o = (int)bkt_o[(u32)b * BCAP + i];
    u32 loc = atomicAdd(&cur[rv & 127], 1u);
    u32 pos = bb + loc;
    col_idx[pos] = o;
    s_perm[pos] = senders[o];
    r_perm[pos] = rv;
    x_perm[pos] = edges_init[o];
  }
}

// ---------------- mega edge kernel: MODE 0=encode+round0, 1=mid, 2=round4+decode ----------
// LDS-minimal variant: ALL W frags read from global (L1/L2-served; W-source proven
// perf-neutral R5/R6/R16) -> LDS ~11.4KB -> occupancy binder is VGPR (5 waves/SIMD,
// 20 waves/CU, +25% vs R16). setprio around MFMA clusters (R15: regalloc lands ~88 VGPR).
// NO occupancy clamp ever (R4/R10/R13: spills, 4-6x loss).
template <int MODE>
__global__ __launch_bounds__(256) void edge_update_kernel(
    bf16_t* __restrict__ e, const bf16_t* __restrict__ n_bf,
    const int* __restrict__ col_idx,
    const int* __restrict__ s_perm, const int* __restrict__ r_perm,
    const float* __restrict__ x_perm,
    const bf16_t* __restrict__ wfr,
    const float* __restrict__ beu1, const float* __restrict__ beu2,
    const float* __restrict__ Wee1, const float* __restrict__ bee1,
    const float* __restrict__ bee2, const float* __restrict__ norm_p,
    const float* __restrict__ bd1, const float* __restrict__ Wd2,
    const float* __restrict__ bd2_p, const float* __restrict__ alpha_p,
    float* __restrict__ out) {
  __shared__ alignas(16) bf16_t tr[4][16][72];  // per-wave transpose buffer
  __shared__ alignas(16) float fconst[448];     // Wee1|bee1|bee2|bd1|Wd2|beu1|beu2
  const int tid = threadIdx.x, lane = tid & 63, wid = tid >> 6;
  const int l15 = lane & 15, lg = lane >> 4;

  for (int c = tid; c < 448; c += 256) {
    float v;
    if (c < 64)       v = Wee1[c];
    else if (c < 128) v = bee1[c - 64];
    else if (c < 192) v = bee2[c - 128];
    else if (c < 256) v = bd1[c - 192];
    else if (c < 320) v = Wd2[c - 256];
    else if (c < 384) v = beu1[c - 320];
    else              v = beu2[c - 384];
    fconst[c] = v;
  }
  __syncthreads();  // only block-wide barrier

  const bf16_t* w1g = wfr;                                        // Weu1 frags 0-23
  const bf16_t* w2g = wfr + (size_t)24 * 512;                     // Weu2 frags
  const bf16_t* wmg = wfr + (size_t)(MODE == 2 ? 40 : 32) * 512;  // Wd1 / Wee2 frags

  float invn = 0.f;
  if constexpr (MODE == 0) invn = 1.0f / *norm_p;
  float nrm = 0.f, alp = 0.f, b2s = 0.f;
  if constexpr (MODE == 2) { nrm = *norm_p; alp = *alpha_p; b2s = *bd2_p; }

  // XCD-aware block swizzle (gridDim.x % 8 == 0)
  const int nb = gridDim.x, cpx = nb >> 3;
  const int bs = (blockIdx.x & 7) * cpx + (blockIdx.x >> 3);
  const int NWAVE = nb * 4;
  const int NG = NE / 16;
  const int g0 = bs * 4 + wid;

  // pipeline state
  int sA, rA, oA, sB, rB, oB, sC, rC, oC;
  float pxA = 0.f, pxB = 0.f, pxC = 0.f;
  bf16x8 eA0, eA1, eB0, eB1, eC0, eC1;
  bf16x8 nA0, nA1, nA2, nA3, nB0, nB1, nB2, nB3;

  auto P1 = [&](int g, int& s, int& r, int& o, float& px, bf16x8& e0, bf16x8& e1) {
    int row = g * 16 + l15;
    s = s_perm[row];
    r = r_perm[row];
    if constexpr (MODE != 1) px = x_perm[row];
    if constexpr (MODE == 2) o = col_idx[row];
    if constexpr (MODE != 0) {
      const bf16x8* er = reinterpret_cast<const bf16x8*>(e + (size_t)row * 64);
      e0 = er[lg];
      e1 = er[4 + lg];
    }
  };
  auto P2 = [&](int s, int r, bf16x8& n0, bf16x8& n1, bf16x8& n2, bf16x8& n3) {
    const bf16x8* sp = reinterpret_cast<const bf16x8*>(n_bf + (size_t)s * 64);
    n0 = sp[lg];
    n1 = sp[4 + lg];
    const bf16x8* rp = reinterpret_cast<const bf16x8*>(n_bf + (size_t)r * 64);
    n2 = rp[lg];
    n3 = rp[4 + lg];
  };

  if (g0 < NG) {
    P1(g0, sA, rA, oA, pxA, eA0, eA1);
    P2(sA, rA, nA0, nA1, nA2, nA3);
    int g1 = g0 + NWAVE;
    if (g1 < NG) P1(g1, sB, rB, oB, pxB, eB0, eB1);
  }

  for (int g = g0; g < NG; g += NWAVE) {
    const int gB = g + NWAVE, gC = g + 2 * NWAVE;
    if (gB < NG) P2(sB, rB, nB0, nB1, nB2, nB3);
    if (gC < NG) P1(gC, sC, rC, oC, pxC, eC0, eC1);

    // === compute on group g ===
    bf16x8 ce0, ce1;
    if constexpr (MODE == 0) {
      float xv = pxA * invn;
      f32x4 wl0 = *reinterpret_cast<const f32x4*>(&fconst[lg * 8]);
      f32x4 wl1 = *reinterpret_cast<const f32x4*>(&fconst[lg * 8 + 4]);
      f32x4 wh0 = *reinterpret_cast<const f32x4*>(&fconst[32 + lg * 8]);
      f32x4 wh1 = *reinterpret_cast<const f32x4*>(&fconst[32 + lg * 8 + 4]);
      f32x4 bl0 = *reinterpret_cast<const f32x4*>(&fconst[64 + lg * 8]);
      f32x4 bl1 = *reinterpret_cast<const f32x4*>(&fconst[64 + lg * 8 + 4]);
      f32x4 bh0 = *reinterpret_cast<const f32x4*>(&fconst[96 + lg * 8]);
      f32x4 bh1 = *reinterpret_cast<const f32x4*>(&fconst[96 + lg * 8 + 4]);
      bf16x8 h0, h1;
#pragma unroll
      for (int i = 0; i < 4; ++i) {
        h0[i]     = (bf16_t)fmaxf(fmaf(xv, wl0[i], bl0[i]), 0.0f);
        h0[4 + i] = (bf16_t)fmaxf(fmaf(xv, wl1[i], bl1[i]), 0.0f);
        h1[i]     = (bf16_t)fmaxf(fmaf(xv, wh0[i], bh0[i]), 0.0f);
        h1[4 + i] = (bf16_t)fmaxf(fmaf(xv, wh1[i], bh1[i]), 0.0f);
      }
      f32x4 ae[4];
#pragma unroll
      for (int nt = 0; nt < 4; ++nt)
        ae[nt] = *reinterpret_cast<const f32x4*>(&fconst[128 + nt * 16 + lg * 4]);
      __builtin_amdgcn_s_setprio(1);
#pragma unroll
      for (int kt = 0; kt < 2; ++kt)
#pragma unroll
        for (int nt = 0; nt < 4; ++nt) {
          bf16x8 wf = *reinterpret_cast<const bf16x8*>(wmg + (size_t)(kt * 4 + nt) * 512 + lane * 8);
          ae[nt] = __builtin_amdgcn_mfma_f32_16x16x32_bf16(wf, kt ? h1 : h0, ae[nt], 0, 0, 0);
        }
      __builtin_amdgcn_s_setprio(0);
#pragma unroll
      for (int nt = 0; nt < 4; ++nt) {
        bf16x4 pk;
#pragma unroll
        for (int r = 0; r < 4; ++r) pk[r] = (bf16_t)ae[nt][r];
        *reinterpret_cast<bf16x4*>(&tr[wid][l15][nt * 16 + lg * 4]) = pk;
      }
      ce0 = *reinterpret_cast<const bf16x8*>(&tr[wid][l15][lg * 8]);
      ce1 = *reinterpret_cast<const bf16x8*>(&tr[wid][l15][32 + lg * 8]);
    } else {
      ce0 = eA0;
      ce1 = eA1;
    }

    // layer 1 (W1 from global)
    f32x4 acc[4];
#pragma unroll
    for (int nt = 0; nt < 4; ++nt)
      acc[nt] = *reinterpret_cast<const f32x4*>(&fconst[320 + nt * 16 + lg * 4]);
    __builtin_amdgcn_s_setprio(1);
#pragma unroll
    for (int kt = 0; kt < 6; ++kt) {
      bf16x8 m = (kt == 0) ? ce0 : (kt == 1) ? ce1 : (kt == 2) ? nA0
               : (kt == 3) ? nA1 : (kt == 4) ? nA2 : nA3;
#pragma unroll
      for (int nt = 0; nt < 4; ++nt) {
        bf16x8 w = *reinterpret_cast<const bf16x8*>(w1g + (size_t)(kt * 4 + nt) * 512 + lane * 8);
        acc[nt] = __builtin_amdgcn_mfma_f32_16x16x32_bf16(w, m, acc[nt], 0, 0, 0);
      }
    }
    __builtin_amdgcn_s_setprio(0);

    // relu -> transpose to B-frag
#pragma unroll
    for (int nt = 0; nt < 4; ++nt) {
      bf16x4 pk;
#pragma unroll
      for (int r = 0; r < 4; ++r) pk[r] = (bf16_t)fmaxf(acc[nt][r], 0.0f);
      *reinterpret_cast<bf16x4*>(&tr[wid][l15][nt * 16 + lg * 4]) = pk;
    }
    bf16x8 hh0 = *reinterpret_cast<const bf16x8*>(&tr[wid][l15][lg * 8]);
    bf16x8 hh1 = *reinterpret_cast<const bf16x8*>(&tr[wid][l15][32 + lg * 8]);

    // layer 2 (W2 from global)
    f32x4 acc2[4];
#pragma unroll
    for (int nt = 0; nt < 4; ++nt)
      acc2[nt] = *reinterpret_cast<const f32x4*>(&fconst[384 + nt * 16 + lg * 4]);
    __builtin_amdgcn_s_setprio(1);
#pragma unroll
    for (int kt = 0; kt < 2; ++kt)
#pragma unroll
      for (int nt = 0; nt < 4; ++nt) {
        bf16x8 w = *reinterpret_cast<const bf16x8*>(w2g + (size_t)(kt * 4 + nt) * 512 + lane * 8);
        acc2[nt] = __builtin_amdgcn_mfma_f32_16x16x32_bf16(w, kt ? hh1 : hh0, acc2[nt], 0, 0, 0);
      }
    __builtin_amdgcn_s_setprio(0);

    if constexpr (MODE == 2) {
      // decoder fused; final e never stored
#pragma unroll
      for (int nt = 0; nt < 4; ++nt) {
        bf16x4 pk;
#pragma unroll
        for (int r = 0; r < 4; ++r) pk[r] = (bf16_t)acc2[nt][r];
        *reinterpret_cast<bf16x4*>(&tr[wid][l15][nt * 16 + lg * 4]) = pk;
      }
      bf16x8 eb0 = *reinterpret_cast<const bf16x8*>(&tr[wid][l15][lg * 8]);
      bf16x8 eb1 = *reinterpret_cast<const bf16x8*>(&tr[wid][l15][32 + lg * 8]);
      f32x4 ad[4];
#pragma unroll
      for (int nt = 0; nt < 4; ++nt)
        ad[nt] = *reinterpret_cast<const f32x4*>(&fconst[192 + nt * 16 + lg * 4]);
      __builtin_amdgcn_s_setprio(1);
#pragma unroll
      for (int kt = 0; kt < 2; ++kt)
#pragma unroll
        for (int nt = 0; nt < 4; ++nt) {
          bf16x8 wf = *reinterpret_cast<const bf16x8*>(wmg + (size_t)(kt * 4 + nt) * 512 + lane * 8);
          ad[nt] = __builtin_amdgcn_mfma_f32_16x16x32_bf16(wf, kt ? eb1 : eb0, ad[nt], 0, 0, 0);
        }
      __builtin_amdgcn_s_setprio(0);
      float s = 0.0f;
#pragma unroll
      for (int nt = 0; nt < 4; ++nt) {
        f32x4 w2 = *reinterpret_cast<const f32x4*>(&fconst[256 + nt * 16 + lg * 4]);
#pragma unroll
        for (int r = 0; r < 4; ++r) s = fmaf(fmaxf(ad[nt][r], 0.0f), w2[r], s);
      }
      s += __shfl_xor(s, 16, 64);
      s += __shfl_xor(s, 32, 64);
      if (lg == 0) {
        float dv = s + b2s;
        out[oA] = (rA >= sA) ? fmaf(alp * nrm, dv, pxA) : 0.0f;
      }
    } else {
      // full-line store: acc2 -> tr -> 2x contiguous 1KB stores (16B/lane)
#pragma unroll
      for (int nt = 0; nt < 4; ++nt) {
        bf16x4 pk;
#pragma unroll
        for (int r = 0; r < 4; ++r) pk[r] = (bf16_t)acc2[nt][r];
        *reinterpret_cast<bf16x4*>(&tr[wid][l15][nt * 16 + lg * 4]) = pk;
      }
      const int rr = lane >> 3, cc = lane & 7;
      bf16x8 w0 = *reinterpret_cast<const bf16x8*>(&tr[wid][rr][cc * 8]);
      bf16x8 w1 = *reinterpret_cast<const bf16x8*>(&tr[wid][8 + rr][cc * 8]);
      *reinterpret_cast<bf16x8*>(e + (size_t)(g * 16 + rr) * 64 + cc * 8) = w0;
      *reinterpret_cast<bf16x8*>(e + (size_t)(g * 16 + 8 + rr) * 64 + cc * 8) = w1;
    }

    // rotate pipeline state
    sA = sB; rA = rB; oA = oB; pxA = pxB;
    eA0 = eB0; eA1 = eB1;
    nA0 = nB0; nA1 = nB1; nA2 = nB2; nA3 = nB3;
    sB = sC; rB = rC; oB = oC; pxB = pxC;
    eB0 = eC0; eB1 = eC1;
  }
}

// ---------------- agg: full-occupancy streaming segment-sum ----------------
__global__ __launch_bounds__(256) void agg_kernel(const bf16_t* __restrict__ e,
                                                  const int* __restrict__ row_ptr,
                                                  bf16_t* __restrict__ agg) {
  const int lane = threadIdx.x & 63, wid = threadIdx.x >> 6;
  const int rsub = lane >> 3;
  const int gw = blockIdx.x * 4 + wid, NWV = gridDim.x * 4;
  for (int node = gw; node < NN; node += NWV) {
    const int p0 = row_ptr[node], cnt = row_ptr[node + 1] - p0;
    float a[8] = {0, 0, 0, 0, 0, 0, 0, 0};
    const bf16x8* bb = reinterpret_cast<const bf16x8*>(e + (size_t)p0 * 64) + lane;
    const int nchunk = (cnt + 7) >> 3;
    int c = 0;
    for (; c + 4 <= nchunk; c += 4) {
      bf16x8 v0 = bb[(size_t)(c + 0) * 64];
      bf16x8 v1 = bb[(size_t)(c + 1) * 64];
      bf16x8 v2 = bb[(size_t)(c + 2) * 64];
      bf16x8 v3 = bb[(size_t)(c + 3) * 64];
      {
#pragma unroll
        for (int i = 0; i < 8; ++i) a[i] += (float)v0[i];
#pragma unroll
        for (int i = 0; i < 8; ++i) a[i] += (float)v1[i];
#pragma unroll
        for (int i = 0; i < 8; ++i) a[i] += (float)v2[i];
      }
      if ((c + 3) * 8 + rsub < cnt) {
#pragma unroll
        for (int i = 0; i < 8; ++i) a[i] += (float)v3[i];
      }
    }
    for (; c < nchunk; ++c) {
      bf16x8 v = bb[(size_t)c * 64];
      if (c * 8 + rsub < cnt) {
#pragma unroll
        for (int i = 0; i < 8; ++i) a[i] += (float)v[i];
      }
    }
#pragma unroll
    for (int i = 0; i < 8; ++i) {
      a[i] += __shfl_xor(a[i], 8, 64);
      a[i] += __shfl_xor(a[i], 16, 64);
      a[i] += __shfl_xor(a[i], 32, 64);
    }
    if (lane < 8) {
      bf16x8 pk;
#pragma unroll
      for (int i = 0; i < 8; ++i) pk[i] = (bf16_t)a[i];
      *reinterpret_cast<bf16x8*>(agg + (size_t)node * 64 + lane * 8) = pk;
    }
  }
}

// ---------------- node MLP via MFMA (16 nodes per wave-task) ----------------
__global__ __launch_bounds__(256) void node_mlp_kernel(
    const bf16_t* __restrict__ agg, const bf16_t* __restrict__ wfr,
    const float* __restrict__ bnu1, const float* __restrict__ bnu2,
    bf16_t* __restrict__ n_bf) {
  __shared__ alignas(16) bf16_t w2s[8 * 512];   // Wnu2 frags (64-71), 8 KB
  __shared__ alignas(16) bf16_t xb[4][16][72];  // per-wave transpose buffer
  const int tid = threadIdx.x, lane = tid & 63, wid = tid >> 6;
  const int l15 = lane & 15, lg = lane >> 4;

  bf16x8 W1r[16];  // Wnu1 frags 48-63 (K=128 -> kt<4, nt<4)
#pragma unroll
  for (int f = 0; f < 16; ++f)
    W1r[f] = *reinterpret_cast<const bf16x8*>(wfr + (size_t)(48 + f) * 512 + lane * 8);
#pragma unroll
  for (int j = 0; j < 2; ++j)
    reinterpret_cast<bf16x8*>(w2s)[j * 256 + tid] =
        reinterpret_cast<const bf16x8*>(wfr + (size_t)64 * 512)[j * 256 + tid];
  __syncthreads();

  f32x4 b1q[4], b2q[4];
#pragma unroll
  for (int nt = 0; nt < 4; ++nt) {
    b1q[nt] = *reinterpret_cast<const f32x4*>(bnu1 + nt * 16 + lg * 4);
    b2q[nt] = *reinterpret_cast<const f32x4*>(bnu2 + nt * 16 + lg * 4);
  }

  const int NT = NN / 16;
  for (int task = blockIdx.x * 4 + wid; task < NT; task += gridDim.x * 4) {
    const int base = task * 16;
    bf16x8 xn0 = *reinterpret_cast<const bf16x8*>(n_bf + (size_t)(base + l15) * 64 + lg * 8);
    bf16x8 xn1 = *reinterpret_cast<const bf16x8*>(n_bf + (size_t)(base + l15) * 64 + 32 + lg * 8);
    bf16x8 xa0 = *reinterpret_cast<const bf16x8*>(agg + (size_t)(base + l15) * 64 + lg * 8);
    bf16x8 xa1 = *reinterpret_cast<const bf16x8*>(agg + (size_t)(base + l15) * 64 + 32 + lg * 8);
    f32x4 acc[4];
#pragma unroll
    for (int nt = 0; nt < 4; ++nt) acc[nt] = b1q[nt];
#pragma unroll
    for (int kt = 0; kt < 4; ++kt) {
      bf16x8 x = (kt == 0) ? xn0 : (kt == 1) ? xn1 : (kt == 2) ? xa0 : xa1;
#pragma unroll
      for (int nt = 0; nt < 4; ++nt)
        acc[nt] = __builtin_amdgcn_mfma_f32_16x16x32_bf16(W1r[kt * 4 + nt], x, acc[nt], 0, 0, 0);
    }
#pragma unroll
    for (int nt = 0; nt < 4; ++nt) {
      bf16x4 pk;
#pragma unroll
      for (int r = 0; r < 4; ++r) pk[r] = (bf16_t)fmaxf(acc[nt][r], 0.0f);
      *reinterpret_cast<bf16x4*>(&xb[wid][l15][nt * 16 + lg * 4]) = pk;
    }
    bf16x8 hh0 = *reinterpret_cast<const bf16x8*>(&xb[wid][l15][lg * 8]);
    bf16x8 hh1 = *reinterpret_cast<const bf16x8*>(&xb[wid][l15][32 + lg * 8]);
    f32x4 acc2[4];
#pragma unroll
    for (int nt = 0; nt < 4; ++nt) acc2[nt] = b2q[nt];
#pragma unroll
    for (int kt = 0; kt < 2; ++kt)
#pragma unroll
      for (int nt = 0; nt < 4; ++nt) {
        bf16x8 w = *reinterpret_cast<const bf16x8*>(w2s + (kt * 4 + nt) * 512 + lane * 8);
        acc2[nt] = __builtin_amdgcn_mfma_f32_16x16x32_bf16(w, kt ? hh1 : hh0, acc2[nt], 0, 0, 0);
      }
#pragma unroll
    for (int nt = 0; nt < 4; ++nt) {
      bf16x4 pk;
#pragma unroll
      for (int r = 0; r < 4; ++r) pk[r] = (bf16_t)acc2[nt][r];
      *reinterpret_cast<bf16x4*>(n_bf + (size_t)(base + l15) * 64 + nt * 16 + lg * 4) = pk;
    }
  }
}

extern "C" void kernel_launch(void* const* d_in, const int* in_sizes, int n_in,
                              void* d_out, int out_size, void* d_ws, size_t ws_size,
                              hipStream_t stream) {
  const float* nodes      = (const float*)d_in[0];
  const float* edges_init = (const float*)d_in[1];
  const int*   receivers  = (const int*)d_in[2];
  const int*   senders    = (const int*)d_in[3];
  const float* Wne1 = (const float*)d_in[4];
  const float* bne1 = (const float*)d_in[5];
  const float* Wne2 = (const float*)d_in[6];
  const float* bne2 = (const float*)d_in[7];
  const float* Wee1 = (const float*)d_in[8];
  const float* bee1 = (const float*)d_in[9];
  const float* Wee2 = (const float*)d_in[10];
  const float* bee2 = (const float*)d_in[11];
  const float* Weu1 = (const float*)d_in[12];
  const float* beu1 = (const float*)d_in[13];
  const float* Weu2 = (const float*)d_in[14];
  const float* beu2 = (const float*)d_in[15];
  const float* Wnu1 = (const float*)d_in[16];
  const float* bnu1 = (const float*)d_in[17];
  const float* Wnu2 = (const float*)d_in[18];
  const float* bnu2 = (const float*)d_in[19];
  const float* Wd1  = (const float*)d_in[20];
  const float* bd1  = (const float*)d_in[21];
  const float* Wd2  = (const float*)d_in[22];
  const float* bd2  = (const float*)d_in[23];
  const float* alpha = (const float*)d_in[24];
  float* out = (float*)d_out;
  (void)in_sizes; (void)n_in; (void)out_size; (void)ws_size;

  char* ws = (char*)d_ws;
  size_t off = 0;
  auto alloc = [&](size_t bytes) -> void* {
    void* p = ws + off;
    off = (off + bytes + 255) & ~(size_t)255;
    return p;
  };
  float*  norm    = (float*)alloc(4);
  u32*    ccur    = (u32*)alloc(sizeof(u32) * 256);
  u32*    bbase   = (u32*)alloc(sizeof(u32) * 256);
  int*    row_ptr = (int*)alloc(sizeof(int) * (NN + 1));
  u16*    bkt_r   = (u16*)alloc(sizeof(u16) * 256 * BCAP);
  u32*    bkt_o   = (u32*)alloc(sizeof(u32) * 256 * BCAP);
  int*    col_idx = (int*)alloc(sizeof(int) * NE);
  int*    s_perm  = (int*)alloc(sizeof(int) * NE);
  int*    r_perm  = (int*)alloc(sizeof(int) * NE);
  float*  x_perm  = (float*)alloc(sizeof(float) * NE);
  bf16_t* n_bf    = (bf16_t*)alloc(sizeof(bf16_t) * (size_t)NN * 64);
  bf16_t* agg     = (bf16_t*)alloc(sizeof(bf16_t) * (size_t)NN * 64);
  bf16_t* e_buf   = (bf16_t*)alloc(sizeof(bf16_t) * (size_t)NE * 64 + 4096);  // +pad: agg tail overread
  bf16_t* wfr     = (bf16_t*)alloc(sizeof(bf16_t) * 72 * 512);

  hipMemsetAsync(norm, 0, 4, stream);
  hipMemsetAsync(ccur, 0, sizeof(u32) * 256, stream);

  prep_encode_kernel<<<8336, 256, 0, stream>>>(Weu1, Weu2, Wee2, Wd1, Wnu1, Wnu2, wfr,
                                               nodes, Wne1, bne1, Wne2, bne2, n_bf);
  coarse_kernel<<<1024, 256, 0, stream>>>(edges_init, receivers, norm, ccur, bkt_r, bkt_o);
  scan256_kernel<<<1, 256, 0, stream>>>(ccur, bbase, row_ptr);
  bucket_kernel<<<256, 1024, 0, stream>>>(ccur, bbase, bkt_r, bkt_o, senders, edges_init,
                                          row_ptr, col_idx, s_perm, r_perm, x_perm);

  edge_update_kernel<0><<<1280, 256, 0, stream>>>(
      e_buf, n_bf, col_idx, s_perm, r_perm, x_perm, wfr, beu1, beu2,
      Wee1, bee1, bee2, norm, bd1, Wd2, bd2, alpha, out);
  for (int t = 1; t <= 4; ++t) {
    agg_kernel<<<2048, 256, 0, stream>>>(e_buf, row_ptr, agg);
    node_mlp_kernel<<<512, 256, 0, stream>>>(agg, wfr, bnu1, bnu2, n_bf);
    if (t < 4)
      edge_update_kernel<1><<<1280, 256, 0, stream>>>(
          e_buf, n_bf, col_idx, s_perm, r_perm, x_perm, wfr, beu1, beu2,
          Wee1, bee1, bee2, norm, bd1, Wd2, bd2, alpha, out);
    else
      edge_update_kernel<2><<<1280, 256, 0, stream>>>(
          e_buf, n_bf, col_idx, s_perm, r_perm, x_perm, wfr, beu1, beu2,
          Wee1, bee1, bee2, norm, bd1, Wd2, bd2, alpha, out);
  }
}

// Round 18
// 530.477 us; speedup vs baseline: 1.1114x; 1.1114x over previous
//
#include <hip/hip_runtime.h>

#define NN 32768
#define NE 1048576
#define BCAP 5120  // per-bucket capacity; mean 4096, sigma 64 -> 16 sigma headroom

typedef __bf16 bf16_t;
typedef __bf16 bf16x8 __attribute__((ext_vector_type(8)));
typedef __bf16 bf16x4 __attribute__((ext_vector_type(4)));
typedef float f32x4 __attribute__((ext_vector_type(4)));
typedef unsigned int u32;
typedef unsigned short u16;

// ---------------- prologue: weight-frag prep | node encoder ----------------
// wfr layout (72 frags x 512), all 16x16 frags (lane: dim=nt*16+(l&15), k=kt*32+(l>>4)*8+i):
//   0-23 Weu1 | 24-31 Weu2 | 32-39 Wee2 | 40-47 Wd1 | 48-63 Wnu1 (K=128) | 64-71 Wnu2
__global__ __launch_bounds__(256) void prep_encode_kernel(
    const float* __restrict__ Weu1, const float* __restrict__ Weu2,
    const float* __restrict__ Wee2, const float* __restrict__ Wd1,
    const float* __restrict__ Wnu1, const float* __restrict__ Wnu2,
    bf16_t* __restrict__ wfr,
    const float* __restrict__ nodes, const float* __restrict__ Wne1,
    const float* __restrict__ bne1, const float* __restrict__ Wne2,
    const float* __restrict__ bne2, bf16_t* __restrict__ n_bf) {
  const int b = blockIdx.x, tid = threadIdx.x;
  if (b < 144) {
    int idx = b * 256 + tid;  // < 36864 = 72 frags
    int i = idx & 7, lane = (idx >> 3) & 63, f = idx >> 9;
    const float* W;
    int fl;
    if (f < 24)      { W = Weu1; fl = f; }
    else if (f < 32) { W = Weu2; fl = f - 24; }
    else if (f < 40) { W = Wee2; fl = f - 32; }
    else if (f < 48) { W = Wd1;  fl = f - 40; }
    else if (f < 64) { W = Wnu1; fl = f - 48; }
    else             { W = Wnu2; fl = f - 64; }
    int kt = fl >> 2, nt = fl & 3;
    int k = kt * 32 + ((lane >> 4) << 3) + i;
    int col = nt * 16 + (lane & 15);
    wfr[idx] = (bf16_t)W[k * 64 + col];
  } else {
    __shared__ float hs[4][64];
    int wid = tid >> 6, k = tid & 63;
    int node = (b - 144) * 4 + wid;
    float x = nodes[node];
    hs[wid][k] = fmaxf(x * Wne1[k] + bne1[k], 0.0f);
    __syncthreads();
    float acc = bne2[k];
#pragma unroll 8
    for (int j = 0; j < 64; ++j) acc = fmaf(hs[wid][j], Wne2[j * 64 + k], acc);
    n_bf[(size_t)node * 64 + k] = (bf16_t)acc;
  }
}

// ---------------- CSR build, level 1: coarse 256-bucket scatter + absmax ----------------
__global__ __launch_bounds__(256) void coarse_kernel(
    const float* __restrict__ edges_init, const int* __restrict__ recv,
    float* __restrict__ norm, u32* __restrict__ ccur,
    u16* __restrict__ bkt_r, u32* __restrict__ bkt_o) {
  __shared__ u32 hist[256];
  __shared__ u32 base[256];
  __shared__ float mred[4];
  const int tid = threadIdx.x, lane = tid & 63, wid = tid >> 6;
  const int idx = blockIdx.x * 256 + tid;
  hist[tid] = 0;
  __syncthreads();
  int4 r = reinterpret_cast<const int4*>(recv)[idx];
  float4 v = reinterpret_cast<const float4*>(edges_init)[idx];
  float m = fmaxf(fmaxf(fabsf(v.x), fabsf(v.y)), fmaxf(fabsf(v.z), fabsf(v.w)));
#pragma unroll
  for (int off = 32; off > 0; off >>= 1) m = fmaxf(m, __shfl_xor(m, off, 64));
  if (lane == 0) mred[wid] = m;
  atomicAdd(&hist[r.x >> 7], 1u);
  atomicAdd(&hist[r.y >> 7], 1u);
  atomicAdd(&hist[r.z >> 7], 1u);
  atomicAdd(&hist[r.w >> 7], 1u);
  __syncthreads();
  if (tid == 0) {
    float mm = fmaxf(fmaxf(mred[0], mred[1]), fmaxf(mred[2], mred[3]));
    atomicMax(reinterpret_cast<u32*>(norm), __float_as_uint(mm));
  }
  u32 h = hist[tid];
  if (h) base[tid] = atomicAdd(&ccur[tid], h);
  hist[tid] = 0;  // reuse as block-local cursor
  __syncthreads();
  const int e0 = idx * 4;
  int rv4[4] = {r.x, r.y, r.z, r.w};
#pragma unroll
  for (int q = 0; q < 4; ++q) {
    int rv = rv4[q], bk = rv >> 7;
    u32 loc = atomicAdd(&hist[bk], 1u);
    u32 pos = (u32)bk * BCAP + base[bk] + loc;
    bkt_r[pos] = (u16)rv;
    bkt_o[pos] = (u32)(e0 + q);
  }
}

__global__ __launch_bounds__(256) void scan256_kernel(const u32* __restrict__ ccur,
                                                      u32* __restrict__ bbase,
                                                      int* __restrict__ row_ptr) {
  __shared__ u32 s[256];
  const int tid = threadIdx.x;
  s[tid] = ccur[tid];
  __syncthreads();
  if (tid == 0) {
    u32 run = 0;
    for (int j = 0; j < 256; ++j) {
      u32 c = s[j];
      s[j] = run;
      run += c;
    }
    row_ptr[NN] = (int)run;
  }
  __syncthreads();
  bbase[tid] = s[tid];
}

__global__ __launch_bounds__(1024) void bucket_kernel(
    const u32* __restrict__ ccur, const u32* __restrict__ bbase,
    const u16* __restrict__ bkt_r, const u32* __restrict__ bkt_o,
    const int* __restrict__ senders, const float* __restrict__ edges_init,
    int* __restrict__ row_ptr, int* __restrict__ col_idx,
    int* __restrict__ s_perm, int* __restrict__ r_perm, float* __restrict__ x_perm) {
  __shared__ u32 hist[128];
  __shared__ u32 cur[128];
  const int b = blockIdx.x, tid = threadIdx.x;
  const u32 sz = ccur[b], bb = bbase[b];
  if (tid < 128) hist[tid] = 0;
  __syncthreads();
  for (u32 i = tid; i < sz; i += 1024) atomicAdd(&hist[bkt_r[(u32)b * BCAP + i] & 127], 1u);
  __syncthreads();
  if (tid == 0) {
    u32 run = 0;
    for (int j = 0; j < 128; ++j) {
      u32 c = hist[j];
      hist[j] = run;
      cur[j] = run;
      run += c;
    }
  }
  __syncthreads();
  if (tid < 128) row_ptr[b * 128 + tid] = (int)(bb + hist[tid]);
  for (u32 i = tid; i < sz; i += 1024) {
    int rv = (int)bkt_r[(u32)b * BCAP + i];
    int o = (int)bkt_o[(u32)b * BCAP + i];
    u32 loc = atomicAdd(&cur[rv & 127], 1u);
    u32 pos = bb + loc;
    col_idx[pos] = o;
    s_perm[pos] = senders[o];
    r_perm[pos] = rv;
    x_perm[pos] = edges_init[o];
  }
}

// ---------------- mega edge kernel: MODE 0=encode+round0, 1=mid, 2=round4+decode ----------
// Interior LDS/VGPR optimum: W1 frags 0-15 in LDS (16KB), frags 16-23 + W2 + mode frags
// from global (R16: 16 global W-streams -> VGPR 88; R17: 32 -> VGPR 132 regression; this
// has 24). LDS ~27KB -> binder is VGPR at 5 waves/SIMD = 20 waves/CU (+25% vs R16).
// setprio around MFMA clusters. NO occupancy clamp ever (R4/R10/R13: spills, 4-6x loss).
template <int MODE>
__global__ __launch_bounds__(256) void edge_update_kernel(
    bf16_t* __restrict__ e, const bf16_t* __restrict__ n_bf,
    const int* __restrict__ col_idx,
    const int* __restrict__ s_perm, const int* __restrict__ r_perm,
    const float* __restrict__ x_perm,
    const bf16_t* __restrict__ wfr,
    const float* __restrict__ beu1, const float* __restrict__ beu2,
    const float* __restrict__ Wee1, const float* __restrict__ bee1,
    const float* __restrict__ bee2, const float* __restrict__ norm_p,
    const float* __restrict__ bd1, const float* __restrict__ Wd2,
    const float* __restrict__ bd2_p, const float* __restrict__ alpha_p,
    float* __restrict__ out) {
  __shared__ alignas(16) bf16_t wstage[16 * 512];  // W1 frags 0-15, 16 KB
  __shared__ alignas(16) bf16_t tr[4][16][72];     // per-wave transpose buffer
  __shared__ alignas(16) float fconst[448];        // Wee1|bee1|bee2|bd1|Wd2|beu1|beu2
  const int tid = threadIdx.x, lane = tid & 63, wid = tid >> 6;
  const int l15 = lane & 15, lg = lane >> 4;

#pragma unroll
  for (int j = 0; j < 4; ++j) {
    int c = j * 256 + tid;  // 1024 chunks of 16B
    int slot = c >> 6, within = c & 63;
    *reinterpret_cast<bf16x8*>(wstage + slot * 512 + within * 8) =
        *reinterpret_cast<const bf16x8*>(wfr + (size_t)slot * 512 + within * 8);
  }
  for (int c = tid; c < 448; c += 256) {
    float v;
    if (c < 64)       v = Wee1[c];
    else if (c < 128) v = bee1[c - 64];
    else if (c < 192) v = bee2[c - 128];
    else if (c < 256) v = bd1[c - 192];
    else if (c < 320) v = Wd2[c - 256];
    else if (c < 384) v = beu1[c - 320];
    else              v = beu2[c - 384];
    fconst[c] = v;
  }
  __syncthreads();  // only block-wide barrier

  const bf16_t* w1hg = wfr + (size_t)16 * 512;                    // Weu1 frags 16-23 (global)
  const bf16_t* w2g = wfr + (size_t)24 * 512;                     // Weu2 frags (global, L1)
  const bf16_t* wmg = wfr + (size_t)(MODE == 2 ? 40 : 32) * 512;  // Wd1 / Wee2 frags

  float invn = 0.f;
  if constexpr (MODE == 0) invn = 1.0f / *norm_p;
  float nrm = 0.f, alp = 0.f, b2s = 0.f;
  if constexpr (MODE == 2) { nrm = *norm_p; alp = *alpha_p; b2s = *bd2_p; }

  // XCD-aware block swizzle (gridDim.x % 8 == 0)
  const int nb = gridDim.x, cpx = nb >> 3;
  const int bs = (blockIdx.x & 7) * cpx + (blockIdx.x >> 3);
  const int NWAVE = nb * 4;
  const int NG = NE / 16;
  const int g0 = bs * 4 + wid;

  // pipeline state
  int sA, rA, oA, sB, rB, oB, sC, rC, oC;
  float pxA = 0.f, pxB = 0.f, pxC = 0.f;
  bf16x8 eA0, eA1, eB0, eB1, eC0, eC1;
  bf16x8 nA0, nA1, nA2, nA3, nB0, nB1, nB2, nB3;

  auto P1 = [&](int g, int& s, int& r, int& o, float& px, bf16x8& e0, bf16x8& e1) {
    int row = g * 16 + l15;
    s = s_perm[row];
    r = r_perm[row];
    if constexpr (MODE != 1) px = x_perm[row];
    if constexpr (MODE == 2) o = col_idx[row];
    if constexpr (MODE != 0) {
      const bf16x8* er = reinterpret_cast<const bf16x8*>(e + (size_t)row * 64);
      e0 = er[lg];
      e1 = er[4 + lg];
    }
  };
  auto P2 = [&](int s, int r, bf16x8& n0, bf16x8& n1, bf16x8& n2, bf16x8& n3) {
    const bf16x8* sp = reinterpret_cast<const bf16x8*>(n_bf + (size_t)s * 64);
    n0 = sp[lg];
    n1 = sp[4 + lg];
    const bf16x8* rp = reinterpret_cast<const bf16x8*>(n_bf + (size_t)r * 64);
    n2 = rp[lg];
    n3 = rp[4 + lg];
  };

  if (g0 < NG) {
    P1(g0, sA, rA, oA, pxA, eA0, eA1);
    P2(sA, rA, nA0, nA1, nA2, nA3);
    int g1 = g0 + NWAVE;
    if (g1 < NG) P1(g1, sB, rB, oB, pxB, eB0, eB1);
  }

  for (int g = g0; g < NG; g += NWAVE) {
    const int gB = g + NWAVE, gC = g + 2 * NWAVE;
    if (gB < NG) P2(sB, rB, nB0, nB1, nB2, nB3);
    if (gC < NG) P1(gC, sC, rC, oC, pxC, eC0, eC1);

    // === compute on group g ===
    bf16x8 ce0, ce1;
    if constexpr (MODE == 0) {
      float xv = pxA * invn;
      f32x4 wl0 = *reinterpret_cast<const f32x4*>(&fconst[lg * 8]);
      f32x4 wl1 = *reinterpret_cast<const f32x4*>(&fconst[lg * 8 + 4]);
      f32x4 wh0 = *reinterpret_cast<const f32x4*>(&fconst[32 + lg * 8]);
      f32x4 wh1 = *reinterpret_cast<const f32x4*>(&fconst[32 + lg * 8 + 4]);
      f32x4 bl0 = *reinterpret_cast<const f32x4*>(&fconst[64 + lg * 8]);
      f32x4 bl1 = *reinterpret_cast<const f32x4*>(&fconst[64 + lg * 8 + 4]);
      f32x4 bh0 = *reinterpret_cast<const f32x4*>(&fconst[96 + lg * 8]);
      f32x4 bh1 = *reinterpret_cast<const f32x4*>(&fconst[96 + lg * 8 + 4]);
      bf16x8 h0, h1;
#pragma unroll
      for (int i = 0; i < 4; ++i) {
        h0[i]     = (bf16_t)fmaxf(fmaf(xv, wl0[i], bl0[i]), 0.0f);
        h0[4 + i] = (bf16_t)fmaxf(fmaf(xv, wl1[i], bl1[i]), 0.0f);
        h1[i]     = (bf16_t)fmaxf(fmaf(xv, wh0[i], bh0[i]), 0.0f);
        h1[4 + i] = (bf16_t)fmaxf(fmaf(xv, wh1[i], bh1[i]), 0.0f);
      }
      f32x4 ae[4];
#pragma unroll
      for (int nt = 0; nt < 4; ++nt)
        ae[nt] = *reinterpret_cast<const f32x4*>(&fconst[128 + nt * 16 + lg * 4]);
      __builtin_amdgcn_s_setprio(1);
#pragma unroll
      for (int kt = 0; kt < 2; ++kt)
#pragma unroll
        for (int nt = 0; nt < 4; ++nt) {
          bf16x8 wf = *reinterpret_cast<const bf16x8*>(wmg + (size_t)(kt * 4 + nt) * 512 + lane * 8);
          ae[nt] = __builtin_amdgcn_mfma_f32_16x16x32_bf16(wf, kt ? h1 : h0, ae[nt], 0, 0, 0);
        }
      __builtin_amdgcn_s_setprio(0);
#pragma unroll
      for (int nt = 0; nt < 4; ++nt) {
        bf16x4 pk;
#pragma unroll
        for (int r = 0; r < 4; ++r) pk[r] = (bf16_t)ae[nt][r];
        *reinterpret_cast<bf16x4*>(&tr[wid][l15][nt * 16 + lg * 4]) = pk;
      }
      ce0 = *reinterpret_cast<const bf16x8*>(&tr[wid][l15][lg * 8]);
      ce1 = *reinterpret_cast<const bf16x8*>(&tr[wid][l15][32 + lg * 8]);
    } else {
      ce0 = eA0;
      ce1 = eA1;
    }

    // layer 1 (W1 kt<4 from LDS, kt 4-5 from global)
    f32x4 acc[4];
#pragma unroll
    for (int nt = 0; nt < 4; ++nt)
      acc[nt] = *reinterpret_cast<const f32x4*>(&fconst[320 + nt * 16 + lg * 4]);
    __builtin_amdgcn_s_setprio(1);
#pragma unroll
    for (int kt = 0; kt < 6; ++kt) {
      bf16x8 m = (kt == 0) ? ce0 : (kt == 1) ? ce1 : (kt == 2) ? nA0
               : (kt == 3) ? nA1 : (kt == 4) ? nA2 : nA3;
#pragma unroll
      for (int nt = 0; nt < 4; ++nt) {
        bf16x8 w = (kt < 4)
            ? *reinterpret_cast<const bf16x8*>(wstage + (kt * 4 + nt) * 512 + lane * 8)
            : *reinterpret_cast<const bf16x8*>(w1hg + (size_t)((kt - 4) * 4 + nt) * 512 + lane * 8);
        acc[nt] = __builtin_amdgcn_mfma_f32_16x16x32_bf16(w, m, acc[nt], 0, 0, 0);
      }
    }
    __builtin_amdgcn_s_setprio(0);

    // relu -> transpose to B-frag
#pragma unroll
    for (int nt = 0; nt < 4; ++nt) {
      bf16x4 pk;
#pragma unroll
      for (int r = 0; r < 4; ++r) pk[r] = (bf16_t)fmaxf(acc[nt][r], 0.0f);
      *reinterpret_cast<bf16x4*>(&tr[wid][l15][nt * 16 + lg * 4]) = pk;
    }
    bf16x8 hh0 = *reinterpret_cast<const bf16x8*>(&tr[wid][l15][lg * 8]);
    bf16x8 hh1 = *reinterpret_cast<const bf16x8*>(&tr[wid][l15][32 + lg * 8]);

    // layer 2 (W2 from global, L1-resident)
    f32x4 acc2[4];
#pragma unroll
    for (int nt = 0; nt < 4; ++nt)
      acc2[nt] = *reinterpret_cast<const f32x4*>(&fconst[384 + nt * 16 + lg * 4]);
    __builtin_amdgcn_s_setprio(1);
#pragma unroll
    for (int kt = 0; kt < 2; ++kt)
#pragma unroll
      for (int nt = 0; nt < 4; ++nt) {
        bf16x8 w = *reinterpret_cast<const bf16x8*>(w2g + (size_t)(kt * 4 + nt) * 512 + lane * 8);
        acc2[nt] = __builtin_amdgcn_mfma_f32_16x16x32_bf16(w, kt ? hh1 : hh0, acc2[nt], 0, 0, 0);
      }
    __builtin_amdgcn_s_setprio(0);

    if constexpr (MODE == 2) {
      // decoder fused; final e never stored
#pragma unroll
      for (int nt = 0; nt < 4; ++nt) {
        bf16x4 pk;
#pragma unroll
        for (int r = 0; r < 4; ++r) pk[r] = (bf16_t)acc2[nt][r];
        *reinterpret_cast<bf16x4*>(&tr[wid][l15][nt * 16 + lg * 4]) = pk;
      }
      bf16x8 eb0 = *reinterpret_cast<const bf16x8*>(&tr[wid][l15][lg * 8]);
      bf16x8 eb1 = *reinterpret_cast<const bf16x8*>(&tr[wid][l15][32 + lg * 8]);
      f32x4 ad[4];
#pragma unroll
      for (int nt = 0; nt < 4; ++nt)
        ad[nt] = *reinterpret_cast<const f32x4*>(&fconst[192 + nt * 16 + lg * 4]);
      __builtin_amdgcn_s_setprio(1);
#pragma unroll
      for (int kt = 0; kt < 2; ++kt)
#pragma unroll
        for (int nt = 0; nt < 4; ++nt) {
          bf16x8 wf = *reinterpret_cast<const bf16x8*>(wmg + (size_t)(kt * 4 + nt) * 512 + lane * 8);
          ad[nt] = __builtin_amdgcn_mfma_f32_16x16x32_bf16(wf, kt ? eb1 : eb0, ad[nt], 0, 0, 0);
        }
      __builtin_amdgcn_s_setprio(0);
      float s = 0.0f;
#pragma unroll
      for (int nt = 0; nt < 4; ++nt) {
        f32x4 w2 = *reinterpret_cast<const f32x4*>(&fconst[256 + nt * 16 + lg * 4]);
#pragma unroll
        for (int r = 0; r < 4; ++r) s = fmaf(fmaxf(ad[nt][r], 0.0f), w2[r], s);
      }
      s += __shfl_xor(s, 16, 64);
      s += __shfl_xor(s, 32, 64);
      if (lg == 0) {
        float dv = s + b2s;
        out[oA] = (rA >= sA) ? fmaf(alp * nrm, dv, pxA) : 0.0f;
      }
    } else {
      // full-line store: acc2 -> tr -> 2x contiguous 1KB stores (16B/lane)
#pragma unroll
      for (int nt = 0; nt < 4; ++nt) {
        bf16x4 pk;
#pragma unroll
        for (int r = 0; r < 4; ++r) pk[r] = (bf16_t)acc2[nt][r];
        *reinterpret_cast<bf16x4*>(&tr[wid][l15][nt * 16 + lg * 4]) = pk;
      }
      const int rr = lane >> 3, cc = lane & 7;
      bf16x8 w0 = *reinterpret_cast<const bf16x8*>(&tr[wid][rr][cc * 8]);
      bf16x8 w1 = *reinterpret_cast<const bf16x8*>(&tr[wid][8 + rr][cc * 8]);
      *reinterpret_cast<bf16x8*>(e + (size_t)(g * 16 + rr) * 64 + cc * 8) = w0;
      *reinterpret_cast<bf16x8*>(e + (size_t)(g * 16 + 8 + rr) * 64 + cc * 8) = w1;
    }

    // rotate pipeline state
    sA = sB; rA = rB; oA = oB; pxA = pxB;
    eA0 = eB0; eA1 = eB1;
    nA0 = nB0; nA1 = nB1; nA2 = nB2; nA3 = nB3;
    sB = sC; rB = rC; oB = oC; pxB = pxC;
    eB0 = eC0; eB1 = eC1;
  }
}

// ---------------- agg: full-occupancy streaming segment-sum ----------------
__global__ __launch_bounds__(256) void agg_kernel(const bf16_t* __restrict__ e,
                                                  const int* __restrict__ row_ptr,
                                                  bf16_t* __restrict__ agg) {
  const int lane = threadIdx.x & 63, wid = threadIdx.x >> 6;
  const int rsub = lane >> 3;
  const int gw = blockIdx.x * 4 + wid, NWV = gridDim.x * 4;
  for (int node = gw; node < NN; node += NWV) {
    const int p0 = row_ptr[node], cnt = row_ptr[node + 1] - p0;
    float a[8] = {0, 0, 0, 0, 0, 0, 0, 0};
    const bf16x8* bb = reinterpret_cast<const bf16x8*>(e + (size_t)p0 * 64) + lane;
    const int nchunk = (cnt + 7) >> 3;
    int c = 0;
    for (; c + 4 <= nchunk; c += 4) {
      bf16x8 v0 = bb[(size_t)(c + 0) * 64];
      bf16x8 v1 = bb[(size_t)(c + 1) * 64];
      bf16x8 v2 = bb[(size_t)(c + 2) * 64];
      bf16x8 v3 = bb[(size_t)(c + 3) * 64];
      {
#pragma unroll
        for (int i = 0; i < 8; ++i) a[i] += (float)v0[i];
#pragma unroll
        for (int i = 0; i < 8; ++i) a[i] += (float)v1[i];
#pragma unroll
        for (int i = 0; i < 8; ++i) a[i] += (float)v2[i];
      }
      if ((c + 3) * 8 + rsub < cnt) {
#pragma unroll
        for (int i = 0; i < 8; ++i) a[i] += (float)v3[i];
      }
    }
    for (; c < nchunk; ++c) {
      bf16x8 v = bb[(size_t)c * 64];
      if (c * 8 + rsub < cnt) {
#pragma unroll
        for (int i = 0; i < 8; ++i) a[i] += (float)v[i];
      }
    }
#pragma unroll
    for (int i = 0; i < 8; ++i) {
      a[i] += __shfl_xor(a[i], 8, 64);
      a[i] += __shfl_xor(a[i], 16, 64);
      a[i] += __shfl_xor(a[i], 32, 64);
    }
    if (lane < 8) {
      bf16x8 pk;
#pragma unroll
      for (int i = 0; i < 8; ++i) pk[i] = (bf16_t)a[i];
      *reinterpret_cast<bf16x8*>(agg + (size_t)node * 64 + lane * 8) = pk;
    }
  }
}

// ---------------- node MLP via MFMA (16 nodes per wave-task) ----------------
__global__ __launch_bounds__(256) void node_mlp_kernel(
    const bf16_t* __restrict__ agg, const bf16_t* __restrict__ wfr,
    const float* __restrict__ bnu1, const float* __restrict__ bnu2,
    bf16_t* __restrict__ n_bf) {
  __shared__ alignas(16) bf16_t w2s[8 * 512];   // Wnu2 frags (64-71), 8 KB
  __shared__ alignas(16) bf16_t xb[4][16][72];  // per-wave transpose buffer
  const int tid = threadIdx.x, lane = tid & 63, wid = tid >> 6;
  const int l15 = lane & 15, lg = lane >> 4;

  bf16x8 W1r[16];  // Wnu1 frags 48-63 (K=128 -> kt<4, nt<4)
#pragma unroll
  for (int f = 0; f < 16; ++f)
    W1r[f] = *reinterpret_cast<const bf16x8*>(wfr + (size_t)(48 + f) * 512 + lane * 8);
#pragma unroll
  for (int j = 0; j < 2; ++j)
    reinterpret_cast<bf16x8*>(w2s)[j * 256 + tid] =
        reinterpret_cast<const bf16x8*>(wfr + (size_t)64 * 512)[j * 256 + tid];
  __syncthreads();

  f32x4 b1q[4], b2q[4];
#pragma unroll
  for (int nt = 0; nt < 4; ++nt) {
    b1q[nt] = *reinterpret_cast<const f32x4*>(bnu1 + nt * 16 + lg * 4);
    b2q[nt] = *reinterpret_cast<const f32x4*>(bnu2 + nt * 16 + lg * 4);
  }

  const int NT = NN / 16;
  for (int task = blockIdx.x * 4 + wid; task < NT; task += gridDim.x * 4) {
    const int base = task * 16;
    bf16x8 xn0 = *reinterpret_cast<const bf16x8*>(n_bf + (size_t)(base + l15) * 64 + lg * 8);
    bf16x8 xn1 = *reinterpret_cast<const bf16x8*>(n_bf + (size_t)(base + l15) * 64 + 32 + lg * 8);
    bf16x8 xa0 = *reinterpret_cast<const bf16x8*>(agg + (size_t)(base + l15) * 64 + lg * 8);
    bf16x8 xa1 = *reinterpret_cast<const bf16x8*>(agg + (size_t)(base + l15) * 64 + 32 + lg * 8);
    f32x4 acc[4];
#pragma unroll
    for (int nt = 0; nt < 4; ++nt) acc[nt] = b1q[nt];
#pragma unroll
    for (int kt = 0; kt < 4; ++kt) {
      bf16x8 x = (kt == 0) ? xn0 : (kt == 1) ? xn1 : (kt == 2) ? xa0 : xa1;
#pragma unroll
      for (int nt = 0; nt < 4; ++nt)
        acc[nt] = __builtin_amdgcn_mfma_f32_16x16x32_bf16(W1r[kt * 4 + nt], x, acc[nt], 0, 0, 0);
    }
#pragma unroll
    for (int nt = 0; nt < 4; ++nt) {
      bf16x4 pk;
#pragma unroll
      for (int r = 0; r < 4; ++r) pk[r] = (bf16_t)fmaxf(acc[nt][r], 0.0f);
      *reinterpret_cast<bf16x4*>(&xb[wid][l15][nt * 16 + lg * 4]) = pk;
    }
    bf16x8 hh0 = *reinterpret_cast<const bf16x8*>(&xb[wid][l15][lg * 8]);
    bf16x8 hh1 = *reinterpret_cast<const bf16x8*>(&xb[wid][l15][32 + lg * 8]);
    f32x4 acc2[4];
#pragma unroll
    for (int nt = 0; nt < 4; ++nt) acc2[nt] = b2q[nt];
#pragma unroll
    for (int kt = 0; kt < 2; ++kt)
#pragma unroll
      for (int nt = 0; nt < 4; ++nt) {
        bf16x8 w = *reinterpret_cast<const bf16x8*>(w2s + (kt * 4 + nt) * 512 + lane * 8);
        acc2[nt] = __builtin_amdgcn_mfma_f32_16x16x32_bf16(w, kt ? hh1 : hh0, acc2[nt], 0, 0, 0);
      }
#pragma unroll
    for (int nt = 0; nt < 4; ++nt) {
      bf16x4 pk;
#pragma unroll
      for (int r = 0; r < 4; ++r) pk[r] = (bf16_t)acc2[nt][r];
      *reinterpret_cast<bf16x4*>(n_bf + (size_t)(base + l15) * 64 + nt * 16 + lg * 4) = pk;
    }
  }
}

extern "C" void kernel_launch(void* const* d_in, const int* in_sizes, int n_in,
                              void* d_out, int out_size, void* d_ws, size_t ws_size,
                              hipStream_t stream) {
  const float* nodes      = (const float*)d_in[0];
  const float* edges_init = (const float*)d_in[1];
  const int*   receivers  = (const int*)d_in[2];
  const int*   senders    = (const int*)d_in[3];
  const float* Wne1 = (const float*)d_in[4];
  const float* bne1 = (const float*)d_in[5];
  const float* Wne2 = (const float*)d_in[6];
  const float* bne2 = (const float*)d_in[7];
  const float* Wee1 = (const float*)d_in[8];
  const float* bee1 = (const float*)d_in[9];
  const float* Wee2 = (const float*)d_in[10];
  const float* bee2 = (const float*)d_in[11];
  const float* Weu1 = (const float*)d_in[12];
  const float* beu1 = (const float*)d_in[13];
  const float* Weu2 = (const float*)d_in[14];
  const float* beu2 = (const float*)d_in[15];
  const float* Wnu1 = (const float*)d_in[16];
  const float* bnu1 = (const float*)d_in[17];
  const float* Wnu2 = (const float*)d_in[18];
  const float* bnu2 = (const float*)d_in[19];
  const float* Wd1  = (const float*)d_in[20];
  const float* bd1  = (const float*)d_in[21];
  const float* Wd2  = (const float*)d_in[22];
  const float* bd2  = (const float*)d_in[23];
  const float* alpha = (const float*)d_in[24];
  float* out = (float*)d_out;
  (void)in_sizes; (void)n_in; (void)out_size; (void)ws_size;

  char* ws = (char*)d_ws;
  size_t off = 0;
  auto alloc = [&](size_t bytes) -> void* {
    void* p = ws + off;
    off = (off + bytes + 255) & ~(size_t)255;
    return p;
  };
  float*  norm    = (float*)alloc(4);
  u32*    ccur    = (u32*)alloc(sizeof(u32) * 256);
  u32*    bbase   = (u32*)alloc(sizeof(u32) * 256);
  int*    row_ptr = (int*)alloc(sizeof(int) * (NN + 1));
  u16*    bkt_r   = (u16*)alloc(sizeof(u16) * 256 * BCAP);
  u32*    bkt_o   = (u32*)alloc(sizeof(u32) * 256 * BCAP);
  int*    col_idx = (int*)alloc(sizeof(int) * NE);
  int*    s_perm  = (int*)alloc(sizeof(int) * NE);
  int*    r_perm  = (int*)alloc(sizeof(int) * NE);
  float*  x_perm  = (float*)alloc(sizeof(float) * NE);
  bf16_t* n_bf    = (bf16_t*)alloc(sizeof(bf16_t) * (size_t)NN * 64);
  bf16_t* agg     = (bf16_t*)alloc(sizeof(bf16_t) * (size_t)NN * 64);
  bf16_t* e_buf   = (bf16_t*)alloc(sizeof(bf16_t) * (size_t)NE * 64 + 4096);  // +pad: agg tail overread
  bf16_t* wfr     = (bf16_t*)alloc(sizeof(bf16_t) * 72 * 512);

  hipMemsetAsync(norm, 0, 4, stream);
  hipMemsetAsync(ccur, 0, sizeof(u32) * 256, stream);

  prep_encode_kernel<<<8336, 256, 0, stream>>>(Weu1, Weu2, Wee2, Wd1, Wnu1, Wnu2, wfr,
                                               nodes, Wne1, bne1, Wne2, bne2, n_bf);
  coarse_kernel<<<1024, 256, 0, stream>>>(edges_init, receivers, norm, ccur, bkt_r, bkt_o);
  scan256_kernel<<<1, 256, 0, stream>>>(ccur, bbase, row_ptr);
  bucket_kernel<<<256, 1024, 0, stream>>>(ccur, bbase, bkt_r, bkt_o, senders, edges_init,
                                          row_ptr, col_idx, s_perm, r_perm, x_perm);

  edge_update_kernel<0><<<1280, 256, 0, stream>>>(
      e_buf, n_bf, col_idx, s_perm, r_perm, x_perm, wfr, beu1, beu2,
      Wee1, bee1, bee2, norm, bd1, Wd2, bd2, alpha, out);
  for (int t = 1; t <= 4; ++t) {
    agg_kernel<<<2048, 256, 0, stream>>>(e_buf, row_ptr, agg);
    node_mlp_kernel<<<512, 256, 0, stream>>>(agg, wfr, bnu1, bnu2, n_bf);
    if (t < 4)
      edge_update_kernel<1><<<1280, 256, 0, stream>>>(
          e_buf, n_bf, col_idx, s_perm, r_perm, x_perm, wfr, beu1, beu2,
          Wee1, bee1, bee2, norm, bd1, Wd2, bd2, alpha, out);
    else
      edge_update_kernel<2><<<1280, 256, 0, stream>>>(
          e_buf, n_bf, col_idx, s_perm, r_perm, x_perm, wfr, beu1, beu2,
          Wee1, bee1, bee2, norm, bd1, Wd2, bd2, alpha, out);
  }
}

// Round 19
// 529.597 us; speedup vs baseline: 1.1133x; 1.0017x over previous
//
#include <hip/hip_runtime.h>

#define NN 32768
#define NE 1048576
#define BCAP 5120  // per-bucket capacity; mean 4096, sigma 64 -> 16 sigma headroom

typedef __bf16 bf16_t;
typedef __bf16 bf16x8 __attribute__((ext_vector_type(8)));
typedef __bf16 bf16x4 __attribute__((ext_vector_type(4)));
typedef float f32x4 __attribute__((ext_vector_type(4)));
typedef unsigned int u32;
typedef unsigned short u16;

// ---------------- prologue: weight-frag prep | node encoder ----------------
// wfr layout (72 frags x 512), all 16x16 frags (lane: dim=nt*16+(l&15), k=kt*32+(l>>4)*8+i):
//   0-23 Weu1 | 24-31 Weu2 | 32-39 Wee2 | 40-47 Wd1 | 48-63 Wnu1 (K=128) | 64-71 Wnu2
__global__ __launch_bounds__(256) void prep_encode_kernel(
    const float* __restrict__ Weu1, const float* __restrict__ Weu2,
    const float* __restrict__ Wee2, const float* __restrict__ Wd1,
    const float* __restrict__ Wnu1, const float* __restrict__ Wnu2,
    bf16_t* __restrict__ wfr,
    const float* __restrict__ nodes, const float* __restrict__ Wne1,
    const float* __restrict__ bne1, const float* __restrict__ Wne2,
    const float* __restrict__ bne2, bf16_t* __restrict__ n_bf) {
  const int b = blockIdx.x, tid = threadIdx.x;
  if (b < 144) {
    int idx = b * 256 + tid;  // < 36864 = 72 frags
    int i = idx & 7, lane = (idx >> 3) & 63, f = idx >> 9;
    const float* W;
    int fl;
    if (f < 24)      { W = Weu1; fl = f; }
    else if (f < 32) { W = Weu2; fl = f - 24; }
    else if (f < 40) { W = Wee2; fl = f - 32; }
    else if (f < 48) { W = Wd1;  fl = f - 40; }
    else if (f < 64) { W = Wnu1; fl = f - 48; }
    else             { W = Wnu2; fl = f - 64; }
    int kt = fl >> 2, nt = fl & 3;
    int k = kt * 32 + ((lane >> 4) << 3) + i;
    int col = nt * 16 + (lane & 15);
    wfr[idx] = (bf16_t)W[k * 64 + col];
  } else {
    __shared__ float hs[4][64];
    int wid = tid >> 6, k = tid & 63;
    int node = (b - 144) * 4 + wid;
    float x = nodes[node];
    hs[wid][k] = fmaxf(x * Wne1[k] + bne1[k], 0.0f);
    __syncthreads();
    float acc = bne2[k];
#pragma unroll 8
    for (int j = 0; j < 64; ++j) acc = fmaf(hs[wid][j], Wne2[j * 64 + k], acc);
    n_bf[(size_t)node * 64 + k] = (bf16_t)acc;
  }
}

// ---------------- CSR build, level 1: coarse 256-bucket scatter + absmax ----------------
__global__ __launch_bounds__(256) void coarse_kernel(
    const float* __restrict__ edges_init, const int* __restrict__ recv,
    float* __restrict__ norm, u32* __restrict__ ccur,
    u16* __restrict__ bkt_r, u32* __restrict__ bkt_o) {
  __shared__ u32 hist[256];
  __shared__ u32 base[256];
  __shared__ float mred[4];
  const int tid = threadIdx.x, lane = tid & 63, wid = tid >> 6;
  const int idx = blockIdx.x * 256 + tid;
  hist[tid] = 0;
  __syncthreads();
  int4 r = reinterpret_cast<const int4*>(recv)[idx];
  float4 v = reinterpret_cast<const float4*>(edges_init)[idx];
  float m = fmaxf(fmaxf(fabsf(v.x), fabsf(v.y)), fmaxf(fabsf(v.z), fabsf(v.w)));
#pragma unroll
  for (int off = 32; off > 0; off >>= 1) m = fmaxf(m, __shfl_xor(m, off, 64));
  if (lane == 0) mred[wid] = m;
  atomicAdd(&hist[r.x >> 7], 1u);
  atomicAdd(&hist[r.y >> 7], 1u);
  atomicAdd(&hist[r.z >> 7], 1u);
  atomicAdd(&hist[r.w >> 7], 1u);
  __syncthreads();
  if (tid == 0) {
    float mm = fmaxf(fmaxf(mred[0], mred[1]), fmaxf(mred[2], mred[3]));
    atomicMax(reinterpret_cast<u32*>(norm), __float_as_uint(mm));
  }
  u32 h = hist[tid];
  if (h) base[tid] = atomicAdd(&ccur[tid], h);
  hist[tid] = 0;  // reuse as block-local cursor
  __syncthreads();
  const int e0 = idx * 4;
  int rv4[4] = {r.x, r.y, r.z, r.w};
#pragma unroll
  for (int q = 0; q < 4; ++q) {
    int rv = rv4[q], bk = rv >> 7;
    u32 loc = atomicAdd(&hist[bk], 1u);
    u32 pos = (u32)bk * BCAP + base[bk] + loc;
    bkt_r[pos] = (u16)rv;
    bkt_o[pos] = (u32)(e0 + q);
  }
}

__global__ __launch_bounds__(256) void scan256_kernel(const u32* __restrict__ ccur,
                                                      u32* __restrict__ bbase,
                                                      int* __restrict__ row_ptr) {
  __shared__ u32 s[256];
  const int tid = threadIdx.x;
  s[tid] = ccur[tid];
  __syncthreads();
  if (tid == 0) {
    u32 run = 0;
    for (int j = 0; j < 256; ++j) {
      u32 c = s[j];
      s[j] = run;
      run += c;
    }
    row_ptr[NN] = (int)run;
  }
  __syncthreads();
  bbase[tid] = s[tid];
}

__global__ __launch_bounds__(1024) void bucket_kernel(
    const u32* __restrict__ ccur, const u32* __restrict__ bbase,
    const u16* __restrict__ bkt_r, const u32* __restrict__ bkt_o,
    const int* __restrict__ senders, const float* __restrict__ edges_init,
    int* __restrict__ row_ptr, int* __restrict__ col_idx,
    int* __restrict__ s_perm, int* __restrict__ r_perm, float* __restrict__ x_perm) {
  __shared__ u32 hist[128];
  __shared__ u32 cur[128];
  const int b = blockIdx.x, tid = threadIdx.x;
  const u32 sz = ccur[b], bb = bbase[b];
  if (tid < 128) hist[tid] = 0;
  __syncthreads();
  for (u32 i = tid; i < sz; i += 1024) atomicAdd(&hist[bkt_r[(u32)b * BCAP + i] & 127], 1u);
  __syncthreads();
  if (tid == 0) {
    u32 run = 0;
    for (int j = 0; j < 128; ++j) {
      u32 c = hist[j];
      hist[j] = run;
      cur[j] = run;
      run += c;
    }
  }
  __syncthreads();
  if (tid < 128) row_ptr[b * 128 + tid] = (int)(bb + hist[tid]);
  for (u32 i = tid; i < sz; i += 1024) {
    int rv = (int)bkt_r[(u32)b * BCAP + i];
    int o = (int)bkt_o[(u32)b * BCAP + i];
    u32 loc = atomicAdd(&cur[rv & 127], 1u);
    u32 pos = bb + loc;
    col_idx[pos] = o;
    s_perm[pos] = senders[o];
    r_perm[pos] = rv;
    x_perm[pos] = edges_init[o];
  }
}

// ---------------- mega edge kernel: MODE 0=encode+round0, 1=mid, 2=round4+decode ----------
// R16 operating point (measured best): setprio around MFMA clusters (regalloc lands ~88
// VGPR, no spill); W1 in LDS (24KB), W2 + mode frags from global (16 global W-streams =
// the LDS/VGPR interior optimum; R17 all-global -> VGPR 132 regression, R18 mid -> 104).
// 4 blocks/CU by LDS. NO occupancy clamp ever (R4/R10/R13: spills, 4-6x loss).
template <int MODE>
__global__ __launch_bounds__(256) void edge_update_kernel(
    bf16_t* __restrict__ e, const bf16_t* __restrict__ n_bf,
    const int* __restrict__ col_idx,
    const int* __restrict__ s_perm, const int* __restrict__ r_perm,
    const float* __restrict__ x_perm,
    const bf16_t* __restrict__ wfr,
    const float* __restrict__ beu1, const float* __restrict__ beu2,
    const float* __restrict__ Wee1, const float* __restrict__ bee1,
    const float* __restrict__ bee2, const float* __restrict__ norm_p,
    const float* __restrict__ bd1, const float* __restrict__ Wd2,
    const float* __restrict__ bd2_p, const float* __restrict__ alpha_p,
    float* __restrict__ out) {
  __shared__ alignas(16) bf16_t wstage[24 * 512];  // W1 only, 24 KB
  __shared__ alignas(16) bf16_t tr[4][16][72];     // per-wave transpose buffer
  __shared__ alignas(16) float fconst[448];        // Wee1|bee1|bee2|bd1|Wd2|beu1|beu2
  const int tid = threadIdx.x, lane = tid & 63, wid = tid >> 6;
  const int l15 = lane & 15, lg = lane >> 4;

#pragma unroll
  for (int j = 0; j < 6; ++j) {
    int c = j * 256 + tid;  // 1536 chunks of 16B
    int slot = c >> 6, within = c & 63;
    *reinterpret_cast<bf16x8*>(wstage + slot * 512 + within * 8) =
        *reinterpret_cast<const bf16x8*>(wfr + (size_t)slot * 512 + within * 8);
  }
  for (int c = tid; c < 448; c += 256) {
    float v;
    if (c < 64)       v = Wee1[c];
    else if (c < 128) v = bee1[c - 64];
    else if (c < 192) v = bee2[c - 128];
    else if (c < 256) v = bd1[c - 192];
    else if (c < 320) v = Wd2[c - 256];
    else if (c < 384) v = beu1[c - 320];
    else              v = beu2[c - 384];
    fconst[c] = v;
  }
  __syncthreads();  // only block-wide barrier

  const bf16_t* w2g = wfr + (size_t)24 * 512;                     // Weu2 frags (global, L1)
  const bf16_t* wmg = wfr + (size_t)(MODE == 2 ? 40 : 32) * 512;  // Wd1 / Wee2 frags

  float invn = 0.f;
  if constexpr (MODE == 0) invn = 1.0f / *norm_p;
  float nrm = 0.f, alp = 0.f, b2s = 0.f;
  if constexpr (MODE == 2) { nrm = *norm_p; alp = *alpha_p; b2s = *bd2_p; }

  // XCD-aware block swizzle (gridDim.x % 8 == 0)
  const int nb = gridDim.x, cpx = nb >> 3;
  const int bs = (blockIdx.x & 7) * cpx + (blockIdx.x >> 3);
  const int NWAVE = nb * 4;
  const int NG = NE / 16;
  const int g0 = bs * 4 + wid;

  // pipeline state
  int sA, rA, oA, sB, rB, oB, sC, rC, oC;
  float pxA = 0.f, pxB = 0.f, pxC = 0.f;
  bf16x8 eA0, eA1, eB0, eB1, eC0, eC1;
  bf16x8 nA0, nA1, nA2, nA3, nB0, nB1, nB2, nB3;

  auto P1 = [&](int g, int& s, int& r, int& o, float& px, bf16x8& e0, bf16x8& e1) {
    int row = g * 16 + l15;
    s = s_perm[row];
    r = r_perm[row];
    if constexpr (MODE != 1) px = x_perm[row];
    if constexpr (MODE == 2) o = col_idx[row];
    if constexpr (MODE != 0) {
      const bf16x8* er = reinterpret_cast<const bf16x8*>(e + (size_t)row * 64);
      e0 = er[lg];
      e1 = er[4 + lg];
    }
  };
  auto P2 = [&](int s, int r, bf16x8& n0, bf16x8& n1, bf16x8& n2, bf16x8& n3) {
    const bf16x8* sp = reinterpret_cast<const bf16x8*>(n_bf + (size_t)s * 64);
    n0 = sp[lg];
    n1 = sp[4 + lg];
    const bf16x8* rp = reinterpret_cast<const bf16x8*>(n_bf + (size_t)r * 64);
    n2 = rp[lg];
    n3 = rp[4 + lg];
  };

  if (g0 < NG) {
    P1(g0, sA, rA, oA, pxA, eA0, eA1);
    P2(sA, rA, nA0, nA1, nA2, nA3);
    int g1 = g0 + NWAVE;
    if (g1 < NG) P1(g1, sB, rB, oB, pxB, eB0, eB1);
  }

  for (int g = g0; g < NG; g += NWAVE) {
    const int gB = g + NWAVE, gC = g + 2 * NWAVE;
    if (gB < NG) P2(sB, rB, nB0, nB1, nB2, nB3);
    if (gC < NG) P1(gC, sC, rC, oC, pxC, eC0, eC1);

    // === compute on group g ===
    bf16x8 ce0, ce1;
    if constexpr (MODE == 0) {
      float xv = pxA * invn;
      f32x4 wl0 = *reinterpret_cast<const f32x4*>(&fconst[lg * 8]);
      f32x4 wl1 = *reinterpret_cast<const f32x4*>(&fconst[lg * 8 + 4]);
      f32x4 wh0 = *reinterpret_cast<const f32x4*>(&fconst[32 + lg * 8]);
      f32x4 wh1 = *reinterpret_cast<const f32x4*>(&fconst[32 + lg * 8 + 4]);
      f32x4 bl0 = *reinterpret_cast<const f32x4*>(&fconst[64 + lg * 8]);
      f32x4 bl1 = *reinterpret_cast<const f32x4*>(&fconst[64 + lg * 8 + 4]);
      f32x4 bh0 = *reinterpret_cast<const f32x4*>(&fconst[96 + lg * 8]);
      f32x4 bh1 = *reinterpret_cast<const f32x4*>(&fconst[96 + lg * 8 + 4]);
      bf16x8 h0, h1;
#pragma unroll
      for (int i = 0; i < 4; ++i) {
        h0[i]     = (bf16_t)fmaxf(fmaf(xv, wl0[i], bl0[i]), 0.0f);
        h0[4 + i] = (bf16_t)fmaxf(fmaf(xv, wl1[i], bl1[i]), 0.0f);
        h1[i]     = (bf16_t)fmaxf(fmaf(xv, wh0[i], bh0[i]), 0.0f);
        h1[4 + i] = (bf16_t)fmaxf(fmaf(xv, wh1[i], bh1[i]), 0.0f);
      }
      f32x4 ae[4];
#pragma unroll
      for (int nt = 0; nt < 4; ++nt)
        ae[nt] = *reinterpret_cast<const f32x4*>(&fconst[128 + nt * 16 + lg * 4]);
      __builtin_amdgcn_s_setprio(1);
#pragma unroll
      for (int kt = 0; kt < 2; ++kt)
#pragma unroll
        for (int nt = 0; nt < 4; ++nt) {
          bf16x8 wf = *reinterpret_cast<const bf16x8*>(wmg + (size_t)(kt * 4 + nt) * 512 + lane * 8);
          ae[nt] = __builtin_amdgcn_mfma_f32_16x16x32_bf16(wf, kt ? h1 : h0, ae[nt], 0, 0, 0);
        }
      __builtin_amdgcn_s_setprio(0);
#pragma unroll
      for (int nt = 0; nt < 4; ++nt) {
        bf16x4 pk;
#pragma unroll
        for (int r = 0; r < 4; ++r) pk[r] = (bf16_t)ae[nt][r];
        *reinterpret_cast<bf16x4*>(&tr[wid][l15][nt * 16 + lg * 4]) = pk;
      }
      ce0 = *reinterpret_cast<const bf16x8*>(&tr[wid][l15][lg * 8]);
      ce1 = *reinterpret_cast<const bf16x8*>(&tr[wid][l15][32 + lg * 8]);
    } else {
      ce0 = eA0;
      ce1 = eA1;
    }

    // layer 1 (W1 from LDS)
    f32x4 acc[4];
#pragma unroll
    for (int nt = 0; nt < 4; ++nt)
      acc[nt] = *reinterpret_cast<const f32x4*>(&fconst[320 + nt * 16 + lg * 4]);
    __builtin_amdgcn_s_setprio(1);
#pragma unroll
    for (int kt = 0; kt < 6; ++kt) {
      bf16x8 m = (kt == 0) ? ce0 : (kt == 1) ? ce1 : (kt == 2) ? nA0
               : (kt == 3) ? nA1 : (kt == 4) ? nA2 : nA3;
#pragma unroll
      for (int nt = 0; nt < 4; ++nt) {
        bf16x8 w = *reinterpret_cast<const bf16x8*>(wstage + (kt * 4 + nt) * 512 + lane * 8);
        acc[nt] = __builtin_amdgcn_mfma_f32_16x16x32_bf16(w, m, acc[nt], 0, 0, 0);
      }
    }
    __builtin_amdgcn_s_setprio(0);

    // relu -> transpose to B-frag
#pragma unroll
    for (int nt = 0; nt < 4; ++nt) {
      bf16x4 pk;
#pragma unroll
      for (int r = 0; r < 4; ++r) pk[r] = (bf16_t)fmaxf(acc[nt][r], 0.0f);
      *reinterpret_cast<bf16x4*>(&tr[wid][l15][nt * 16 + lg * 4]) = pk;
    }
    bf16x8 hh0 = *reinterpret_cast<const bf16x8*>(&tr[wid][l15][lg * 8]);
    bf16x8 hh1 = *reinterpret_cast<const bf16x8*>(&tr[wid][l15][32 + lg * 8]);

    // layer 2 (W2 from global, L1-resident)
    f32x4 acc2[4];
#pragma unroll
    for (int nt = 0; nt < 4; ++nt)
      acc2[nt] = *reinterpret_cast<const f32x4*>(&fconst[384 + nt * 16 + lg * 4]);
    __builtin_amdgcn_s_setprio(1);
#pragma unroll
    for (int kt = 0; kt < 2; ++kt)
#pragma unroll
      for (int nt = 0; nt < 4; ++nt) {
        bf16x8 w = *reinterpret_cast<const bf16x8*>(w2g + (size_t)(kt * 4 + nt) * 512 + lane * 8);
        acc2[nt] = __builtin_amdgcn_mfma_f32_16x16x32_bf16(w, kt ? hh1 : hh0, acc2[nt], 0, 0, 0);
      }
    __builtin_amdgcn_s_setprio(0);

    if constexpr (MODE == 2) {
      // decoder fused; final e never stored
#pragma unroll
      for (int nt = 0; nt < 4; ++nt) {
        bf16x4 pk;
#pragma unroll
        for (int r = 0; r < 4; ++r) pk[r] = (bf16_t)acc2[nt][r];
        *reinterpret_cast<bf16x4*>(&tr[wid][l15][nt * 16 + lg * 4]) = pk;
      }
      bf16x8 eb0 = *reinterpret_cast<const bf16x8*>(&tr[wid][l15][lg * 8]);
      bf16x8 eb1 = *reinterpret_cast<const bf16x8*>(&tr[wid][l15][32 + lg * 8]);
      f32x4 ad[4];
#pragma unroll
      for (int nt = 0; nt < 4; ++nt)
        ad[nt] = *reinterpret_cast<const f32x4*>(&fconst[192 + nt * 16 + lg * 4]);
      __builtin_amdgcn_s_setprio(1);
#pragma unroll
      for (int kt = 0; kt < 2; ++kt)
#pragma unroll
        for (int nt = 0; nt < 4; ++nt) {
          bf16x8 wf = *reinterpret_cast<const bf16x8*>(wmg + (size_t)(kt * 4 + nt) * 512 + lane * 8);
          ad[nt] = __builtin_amdgcn_mfma_f32_16x16x32_bf16(wf, kt ? eb1 : eb0, ad[nt], 0, 0, 0);
        }
      __builtin_amdgcn_s_setprio(0);
      float s = 0.0f;
#pragma unroll
      for (int nt = 0; nt < 4; ++nt) {
        f32x4 w2 = *reinterpret_cast<const f32x4*>(&fconst[256 + nt * 16 + lg * 4]);
#pragma unroll
        for (int r = 0; r < 4; ++r) s = fmaf(fmaxf(ad[nt][r], 0.0f), w2[r], s);
      }
      s += __shfl_xor(s, 16, 64);
      s += __shfl_xor(s, 32, 64);
      if (lg == 0) {
        float dv = s + b2s;
        out[oA] = (rA >= sA) ? fmaf(alp * nrm, dv, pxA) : 0.0f;
      }
    } else {
      // full-line store: acc2 -> tr -> 2x contiguous 1KB stores (16B/lane)
#pragma unroll
      for (int nt = 0; nt < 4; ++nt) {
        bf16x4 pk;
#pragma unroll
        for (int r = 0; r < 4; ++r) pk[r] = (bf16_t)acc2[nt][r];
        *reinterpret_cast<bf16x4*>(&tr[wid][l15][nt * 16 + lg * 4]) = pk;
      }
      const int rr = lane >> 3, cc = lane & 7;
      bf16x8 w0 = *reinterpret_cast<const bf16x8*>(&tr[wid][rr][cc * 8]);
      bf16x8 w1 = *reinterpret_cast<const bf16x8*>(&tr[wid][8 + rr][cc * 8]);
      *reinterpret_cast<bf16x8*>(e + (size_t)(g * 16 + rr) * 64 + cc * 8) = w0;
      *reinterpret_cast<bf16x8*>(e + (size_t)(g * 16 + 8 + rr) * 64 + cc * 8) = w1;
    }

    // rotate pipeline state
    sA = sB; rA = rB; oA = oB; pxA = pxB;
    eA0 = eB0; eA1 = eB1;
    nA0 = nB0; nA1 = nB1; nA2 = nB2; nA3 = nB3;
    sB = sC; rB = rC; oB = oC; pxB = pxC;
    eB0 = eC0; eB1 = eC1;
  }
}

// ---------------- agg: full-occupancy streaming segment-sum ----------------
__global__ __launch_bounds__(256) void agg_kernel(const bf16_t* __restrict__ e,
                                                  const int* __restrict__ row_ptr,
                                                  bf16_t* __restrict__ agg) {
  const int lane = threadIdx.x & 63, wid = threadIdx.x >> 6;
  const int rsub = lane >> 3;
  const int gw = blockIdx.x * 4 + wid, NWV = gridDim.x * 4;
  for (int node = gw; node < NN; node += NWV) {
    const int p0 = row_ptr[node], cnt = row_ptr[node + 1] - p0;
    float a[8] = {0, 0, 0, 0, 0, 0, 0, 0};
    const bf16x8* bb = reinterpret_cast<const bf16x8*>(e + (size_t)p0 * 64) + lane;
    const int nchunk = (cnt + 7) >> 3;
    int c = 0;
    for (; c + 4 <= nchunk; c += 4) {
      bf16x8 v0 = bb[(size_t)(c + 0) * 64];
      bf16x8 v1 = bb[(size_t)(c + 1) * 64];
      bf16x8 v2 = bb[(size_t)(c + 2) * 64];
      bf16x8 v3 = bb[(size_t)(c + 3) * 64];
      {
#pragma unroll
        for (int i = 0; i < 8; ++i) a[i] += (float)v0[i];
#pragma unroll
        for (int i = 0; i < 8; ++i) a[i] += (float)v1[i];
#pragma unroll
        for (int i = 0; i < 8; ++i) a[i] += (float)v2[i];
      }
      if ((c + 3) * 8 + rsub < cnt) {
#pragma unroll
        for (int i = 0; i < 8; ++i) a[i] += (float)v3[i];
      }
    }
    for (; c < nchunk; ++c) {
      bf16x8 v = bb[(size_t)c * 64];
      if (c * 8 + rsub < cnt) {
#pragma unroll
        for (int i = 0; i < 8; ++i) a[i] += (float)v[i];
      }
    }
#pragma unroll
    for (int i = 0; i < 8; ++i) {
      a[i] += __shfl_xor(a[i], 8, 64);
      a[i] += __shfl_xor(a[i], 16, 64);
      a[i] += __shfl_xor(a[i], 32, 64);
    }
    if (lane < 8) {
      bf16x8 pk;
#pragma unroll
      for (int i = 0; i < 8; ++i) pk[i] = (bf16_t)a[i];
      *reinterpret_cast<bf16x8*>(agg + (size_t)node * 64 + lane * 8) = pk;
    }
  }
}

// ---------------- node MLP via MFMA (16 nodes per wave-task) ----------------
__global__ __launch_bounds__(256) void node_mlp_kernel(
    const bf16_t* __restrict__ agg, const bf16_t* __restrict__ wfr,
    const float* __restrict__ bnu1, const float* __restrict__ bnu2,
    bf16_t* __restrict__ n_bf) {
  __shared__ alignas(16) bf16_t w2s[8 * 512];   // Wnu2 frags (64-71), 8 KB
  __shared__ alignas(16) bf16_t xb[4][16][72];  // per-wave transpose buffer
  const int tid = threadIdx.x, lane = tid & 63, wid = tid >> 6;
  const int l15 = lane & 15, lg = lane >> 4;

  bf16x8 W1r[16];  // Wnu1 frags 48-63 (K=128 -> kt<4, nt<4)
#pragma unroll
  for (int f = 0; f < 16; ++f)
    W1r[f] = *reinterpret_cast<const bf16x8*>(wfr + (size_t)(48 + f) * 512 + lane * 8);
#pragma unroll
  for (int j = 0; j < 2; ++j)
    reinterpret_cast<bf16x8*>(w2s)[j * 256 + tid] =
        reinterpret_cast<const bf16x8*>(wfr + (size_t)64 * 512)[j * 256 + tid];
  __syncthreads();

  f32x4 b1q[4], b2q[4];
#pragma unroll
  for (int nt = 0; nt < 4; ++nt) {
    b1q[nt] = *reinterpret_cast<const f32x4*>(bnu1 + nt * 16 + lg * 4);
    b2q[nt] = *reinterpret_cast<const f32x4*>(bnu2 + nt * 16 + lg * 4);
  }

  const int NT = NN / 16;
  for (int task = blockIdx.x * 4 + wid; task < NT; task += gridDim.x * 4) {
    const int base = task * 16;
    bf16x8 xn0 = *reinterpret_cast<const bf16x8*>(n_bf + (size_t)(base + l15) * 64 + lg * 8);
    bf16x8 xn1 = *reinterpret_cast<const bf16x8*>(n_bf + (size_t)(base + l15) * 64 + 32 + lg * 8);
    bf16x8 xa0 = *reinterpret_cast<const bf16x8*>(agg + (size_t)(base + l15) * 64 + lg * 8);
    bf16x8 xa1 = *reinterpret_cast<const bf16x8*>(agg + (size_t)(base + l15) * 64 + 32 + lg * 8);
    f32x4 acc[4];
#pragma unroll
    for (int nt = 0; nt < 4; ++nt) acc[nt] = b1q[nt];
#pragma unroll
    for (int kt = 0; kt < 4; ++kt) {
      bf16x8 x = (kt == 0) ? xn0 : (kt == 1) ? xn1 : (kt == 2) ? xa0 : xa1;
#pragma unroll
      for (int nt = 0; nt < 4; ++nt)
        acc[nt] = __builtin_amdgcn_mfma_f32_16x16x32_bf16(W1r[kt * 4 + nt], x, acc[nt], 0, 0, 0);
    }
#pragma unroll
    for (int nt = 0; nt < 4; ++nt) {
      bf16x4 pk;
#pragma unroll
      for (int r = 0; r < 4; ++r) pk[r] = (bf16_t)fmaxf(acc[nt][r], 0.0f);
      *reinterpret_cast<bf16x4*>(&xb[wid][l15][nt * 16 + lg * 4]) = pk;
    }
    bf16x8 hh0 = *reinterpret_cast<const bf16x8*>(&xb[wid][l15][lg * 8]);
    bf16x8 hh1 = *reinterpret_cast<const bf16x8*>(&xb[wid][l15][32 + lg * 8]);
    f32x4 acc2[4];
#pragma unroll
    for (int nt = 0; nt < 4; ++nt) acc2[nt] = b2q[nt];
#pragma unroll
    for (int kt = 0; kt < 2; ++kt)
#pragma unroll
      for (int nt = 0; nt < 4; ++nt) {
        bf16x8 w = *reinterpret_cast<const bf16x8*>(w2s + (kt * 4 + nt) * 512 + lane * 8);
        acc2[nt] = __builtin_amdgcn_mfma_f32_16x16x32_bf16(w, kt ? hh1 : hh0, acc2[nt], 0, 0, 0);
      }
#pragma unroll
    for (int nt = 0; nt < 4; ++nt) {
      bf16x4 pk;
#pragma unroll
      for (int r = 0; r < 4; ++r) pk[r] = (bf16_t)acc2[nt][r];
      *reinterpret_cast<bf16x4*>(n_bf + (size_t)(base + l15) * 64 + nt * 16 + lg * 4) = pk;
    }
  }
}

extern "C" void kernel_launch(void* const* d_in, const int* in_sizes, int n_in,
                              void* d_out, int out_size, void* d_ws, size_t ws_size,
                              hipStream_t stream) {
  const float* nodes      = (const float*)d_in[0];
  const float* edges_init = (const float*)d_in[1];
  const int*   receivers  = (const int*)d_in[2];
  const int*   senders    = (const int*)d_in[3];
  const float* Wne1 = (const float*)d_in[4];
  const float* bne1 = (const float*)d_in[5];
  const float* Wne2 = (const float*)d_in[6];
  const float* bne2 = (const float*)d_in[7];
  const float* Wee1 = (const float*)d_in[8];
  const float* bee1 = (const float*)d_in[9];
  const float* Wee2 = (const float*)d_in[10];
  const float* bee2 = (const float*)d_in[11];
  const float* Weu1 = (const float*)d_in[12];
  const float* beu1 = (const float*)d_in[13];
  const float* Weu2 = (const float*)d_in[14];
  const float* beu2 = (const float*)d_in[15];
  const float* Wnu1 = (const float*)d_in[16];
  const float* bnu1 = (const float*)d_in[17];
  const float* Wnu2 = (const float*)d_in[18];
  const float* bnu2 = (const float*)d_in[19];
  const float* Wd1  = (const float*)d_in[20];
  const float* bd1  = (const float*)d_in[21];
  const float* Wd2  = (const float*)d_in[22];
  const float* bd2  = (const float*)d_in[23];
  const float* alpha = (const float*)d_in[24];
  float* out = (float*)d_out;
  (void)in_sizes; (void)n_in; (void)out_size; (void)ws_size;

  char* ws = (char*)d_ws;
  size_t off = 0;
  auto alloc = [&](size_t bytes) -> void* {
    void* p = ws + off;
    off = (off + bytes + 255) & ~(size_t)255;
    return p;
  };
  float*  norm    = (float*)alloc(4);
  u32*    ccur    = (u32*)alloc(sizeof(u32) * 256);
  u32*    bbase   = (u32*)alloc(sizeof(u32) * 256);
  int*    row_ptr = (int*)alloc(sizeof(int) * (NN + 1));
  u16*    bkt_r   = (u16*)alloc(sizeof(u16) * 256 * BCAP);
  u32*    bkt_o   = (u32*)alloc(sizeof(u32) * 256 * BCAP);
  int*    col_idx = (int*)alloc(sizeof(int) * NE);
  int*    s_perm  = (int*)alloc(sizeof(int) * NE);
  int*    r_perm  = (int*)alloc(sizeof(int) * NE);
  float*  x_perm  = (float*)alloc(sizeof(float) * NE);
  bf16_t* n_bf    = (bf16_t*)alloc(sizeof(bf16_t) * (size_t)NN * 64);
  bf16_t* agg     = (bf16_t*)alloc(sizeof(bf16_t) * (size_t)NN * 64);
  bf16_t* e_buf   = (bf16_t*)alloc(sizeof(bf16_t) * (size_t)NE * 64 + 4096);  // +pad: agg tail overread
  bf16_t* wfr     = (bf16_t*)alloc(sizeof(bf16_t) * 72 * 512);

  hipMemsetAsync(norm, 0, 4, stream);
  hipMemsetAsync(ccur, 0, sizeof(u32) * 256, stream);

  prep_encode_kernel<<<8336, 256, 0, stream>>>(Weu1, Weu2, Wee2, Wd1, Wnu1, Wnu2, wfr,
                                               nodes, Wne1, bne1, Wne2, bne2, n_bf);
  coarse_kernel<<<1024, 256, 0, stream>>>(edges_init, receivers, norm, ccur, bkt_r, bkt_o);
  scan256_kernel<<<1, 256, 0, stream>>>(ccur, bbase, row_ptr);
  bucket_kernel<<<256, 1024, 0, stream>>>(ccur, bbase, bkt_r, bkt_o, senders, edges_init,
                                          row_ptr, col_idx, s_perm, r_perm, x_perm);

  edge_update_kernel<0><<<1024, 256, 0, stream>>>(
      e_buf, n_bf, col_idx, s_perm, r_perm, x_perm, wfr, beu1, beu2,
      Wee1, bee1, bee2, norm, bd1, Wd2, bd2, alpha, out);
  for (int t = 1; t <= 4; ++t) {
    agg_kernel<<<2048, 256, 0, stream>>>(e_buf, row_ptr, agg);
    node_mlp_kernel<<<512, 256, 0, stream>>>(agg, wfr, bnu1, bnu2, n_bf);
    if (t < 4)
      edge_update_kernel<1><<<1024, 256, 0, stream>>>(
          e_buf, n_bf, col_idx, s_perm, r_perm, x_perm, wfr, beu1, beu2,
          Wee1, bee1, bee2, norm, bd1, Wd2, bd2, alpha, out);
    else
      edge_update_kernel<2><<<1024, 256, 0, stream>>>(
          e_buf, n_bf, col_idx, s_perm, r_perm, x_perm, wfr, beu1, beu2,
          Wee1, bee1, bee2, norm, bd1, Wd2, bd2, alpha, out);
  }
}